// Round 1
// baseline (1345.903 us; speedup 1.0000x reference)
//
#include <hip/hip_runtime.h>
#include <math.h>

#define B_   8
#define NTOK 5376
#define CIN  384
#define CH   768
#define M_   (B_*NTOK)   // 43008

typedef unsigned short u16;
typedef unsigned int   u32;

using bf16x8 = __attribute__((ext_vector_type(8))) short;
using f32x4  = __attribute__((ext_vector_type(4))) float;

__device__ __forceinline__ u16 f2bf(float f) {
    union { float f; u32 u; } v; v.f = f;
    u32 r = v.u + 0x7fffu + ((v.u >> 16) & 1u);   // RNE (finite inputs)
    return (u16)(r >> 16);
}
__device__ __forceinline__ float bf2f(u16 u) {
    union { u32 u; float f; } v; v.u = ((u32)u) << 16;
    return v.f;
}

// ---------------------------------------------------------------- converts
__global__ void k_cvt_x(const float* __restrict__ x, u16* __restrict__ xb, int n4) {
    int i = blockIdx.x * blockDim.x + threadIdx.x;
    if (i >= n4) return;
    float4 v = ((const float4*)x)[i];
    ushort4 o;
    o.x = f2bf(v.x); o.y = f2bf(v.y); o.z = f2bf(v.z); o.w = f2bf(v.w);
    ((ushort4*)xb)[i] = o;
}

// src: (K, N) f32 row-major  ->  dst: (N, K) bf16 row-major
__global__ void k_cvt_wT(const float* __restrict__ w, u16* __restrict__ wT, int K, int N) {
    int i = blockIdx.x * blockDim.x + threadIdx.x;
    if (i >= N * K) return;
    int n = i / K, k = i % K;
    wT[i] = f2bf(w[k * N + n]);
}

// ---------------------------------------------------------------- GEMM
// C[M,N] = A[M,K] @ Bt[N,K]^T + bias, A/Bt bf16, acc f32.
// 128x128 tile, BK=64, 4 waves (2x2), 16x16x32 MFMA, global_load_lds staging.
#define BM 128
#define BN 128
#define BK 64

template<bool OUT_BF16>
__launch_bounds__(256)
__global__ void gemm_bf16_kernel(const u16* __restrict__ A, const u16* __restrict__ Bt,
                                 const float* __restrict__ bias, void* __restrict__ Cout,
                                 int M, int N, int K) {
    __shared__ __align__(16) u16 sA[BM * BK];
    __shared__ __align__(16) u16 sB[BN * BK];
    const int mt = blockIdx.x, nt = blockIdx.y;
    const int tid = threadIdx.x;
    const int wave = tid >> 6, lane = tid & 63;
    const int wm = wave >> 1, wn = wave & 1;
    const int row0 = mt * BM, col0 = nt * BN;
    const int lr = lane & 15, lk = lane >> 4;

    f32x4 acc[4][4];
#pragma unroll
    for (int m = 0; m < 4; m++)
#pragma unroll
        for (int n = 0; n < 4; n++) acc[m][n] = (f32x4){0.f, 0.f, 0.f, 0.f};

    const int r_st = (tid) >> 3;        // staging row for this thread's granule
    const int ks_st = (tid) & 7;        // 16B-granule within row (8 bf16)

    const int KT = K / BK;
    for (int kt = 0; kt < KT; ++kt) {
        const int k0 = kt * BK;
        // stage A and B tiles: 1024 granules each, 256 threads x 4 iters
#pragma unroll
        for (int it = 0; it < 4; ++it) {
            int g  = it * 256 + tid;
            int r  = g >> 3;
            int ks = g & 7;
            const u16* gA = A + (size_t)(row0 + r) * K + k0 + ks * 8;
            const u16* gB = Bt + (size_t)(col0 + r) * K + k0 + ks * 8;
            u16* lA = sA + (size_t)(it * 256 + wave * 64) * 8;   // wave-uniform base
            u16* lB = sB + (size_t)(it * 256 + wave * 64) * 8;
            __builtin_amdgcn_global_load_lds(
                (const __attribute__((address_space(1))) u32*)(const void*)gA,
                (__attribute__((address_space(3))) u32*)(void*)lA, 16, 0, 0);
            __builtin_amdgcn_global_load_lds(
                (const __attribute__((address_space(1))) u32*)(const void*)gB,
                (__attribute__((address_space(3))) u32*)(void*)lB, 16, 0, 0);
        }
        __syncthreads();   // drains vmcnt before any wave reads LDS
#pragma unroll
        for (int kk = 0; kk < 2; ++kk) {
            bf16x8 af[4], bfr[4];
#pragma unroll
            for (int m = 0; m < 4; m++)
                af[m] = *(const bf16x8*)&sA[(wm * 64 + m * 16 + lr) * BK + kk * 32 + lk * 8];
#pragma unroll
            for (int n = 0; n < 4; n++)
                bfr[n] = *(const bf16x8*)&sB[(wn * 64 + n * 16 + lr) * BK + kk * 32 + lk * 8];
#pragma unroll
            for (int m = 0; m < 4; m++)
#pragma unroll
                for (int n = 0; n < 4; n++)
                    acc[m][n] = __builtin_amdgcn_mfma_f32_16x16x32_bf16(af[m], bfr[n], acc[m][n], 0, 0, 0);
        }
        __syncthreads();
    }

    // epilogue: D row = (lane>>4)*4 + r, col = lane&15  [m89-verified layout]
#pragma unroll
    for (int m = 0; m < 4; m++) {
#pragma unroll
        for (int n = 0; n < 4; n++) {
            int col = col0 + wn * 64 + n * 16 + lr;
            float bv = bias[col];
#pragma unroll
            for (int r = 0; r < 4; r++) {
                int row = row0 + wm * 64 + m * 16 + lk * 4 + r;
                float v = acc[m][n][r] + bv;
                if (OUT_BF16)
                    ((u16*)Cout)[(size_t)row * N + col] = f2bf(v);
                else
                    ((float*)Cout)[(size_t)row * N + col] = v;
            }
        }
    }
}

// ---------------------------------------------------------------- conv helpers
__device__ __forceinline__ float conv_at(const u16* __restrict__ h, const float* wreg, float dwb,
                                         int b, int tokbase, int hw, int lw, int p, int c) {
    int y = p >> lw, x = p & (hw - 1);
    float v = dwb;
#pragma unroll
    for (int ky = 0; ky < 3; ++ky) {
        int yy = y + ky - 1;
        if ((unsigned)yy >= (unsigned)hw) continue;
        const u16* hr = h + ((size_t)(b * NTOK + tokbase + (yy << lw))) * CH + c;
#pragma unroll
        for (int kx = 0; kx < 3; ++kx) {
            int xx = x + kx - 1;
            if ((unsigned)xx >= (unsigned)hw) continue;
            v += wreg[ky * 3 + kx] * bf2f(hr[(ptrdiff_t)xx * CH]);
        }
    }
    return v;
}

__device__ __forceinline__ void decode_slot(int slot, int& s, int& chunk, int& tokbase, int& lw) {
    if (slot < 16)      { s = 0; chunk = slot;      tokbase = 0;    lw = 6; }
    else if (slot < 20) { s = 1; chunk = slot - 16; tokbase = 4096; lw = 5; }
    else                { s = 2; chunk = 0;         tokbase = 5120; lw = 4; }
}

// depthwise conv (recompute) + per-chunk partial sum/max.  grid (21, 3, 8)
__global__ void k_conv_stats(const u16* __restrict__ h, const float* __restrict__ dw_w,
                             const float* __restrict__ dw_b,
                             float* __restrict__ psum, float* __restrict__ pmax) {
    int slot = blockIdx.x, cchunk = blockIdx.y, b = blockIdx.z;
    int s, chunk, tokbase, lw;
    decode_slot(slot, s, chunk, tokbase, lw);
    int hw = 1 << lw;
    int c = cchunk * 256 + threadIdx.x;
    float wreg[9];
#pragma unroll
    for (int i = 0; i < 9; i++) wreg[i] = dw_w[c * 9 + i];
    float dwb = dw_b[c];
    int p0 = chunk * 256;
    float sm = 0.f, mx = -3.4e38f;
    for (int p = p0; p < p0 + 256; ++p) {
        float v = conv_at(h, wreg, dwb, b, tokbase, hw, lw, p, c);
        sm += v;
        mx = fmaxf(mx, v);
    }
    psum[((size_t)slot * 8 + b) * CH + c] = sm;
    pmax[((size_t)slot * 8 + b) * CH + c] = mx;
}

// reduce partials -> gate softmax, channel conv1 gates, blended scale. grid (3, 8)
__global__ void k_scale(const float* __restrict__ psum, const float* __restrict__ pmax,
                        const float* __restrict__ gate_w, const float* __restrict__ gate_b,
                        const float* __restrict__ ca_w, const float* __restrict__ ra_w,
                        float* __restrict__ scale) {
    int s = blockIdx.x, b = blockIdx.y;
    int tid = threadIdx.x;
    int slot0  = (s == 0) ? 0 : (s == 1) ? 16 : 20;
    int nslots = (s == 0) ? 16 : (s == 1) ? 4 : 1;
    float npos = (s == 0) ? 4096.f : (s == 1) ? 1024.f : 256.f;
    __shared__ float pooled[CH];
    __shared__ float rl[4][2];
    float l0 = 0.f, l1 = 0.f;
#pragma unroll
    for (int j = 0; j < 3; j++) {
        int c = j * 256 + tid;
        float smv = 0.f, mxv = -3.4e38f;
        for (int t = 0; t < nslots; t++) {
            size_t idx = ((size_t)(slot0 + t) * 8 + b) * CH + c;
            smv += psum[idx];
            mxv = fmaxf(mxv, pmax[idx]);
        }
        float avg = smv / npos;
        pooled[c] = avg + mxv;
        l0 += avg * gate_w[c * 2 + 0];
        l1 += avg * gate_w[c * 2 + 1];
    }
    for (int off = 32; off; off >>= 1) {
        l0 += __shfl_down(l0, off);
        l1 += __shfl_down(l1, off);
    }
    int wave = tid >> 6, lane = tid & 63;
    if (lane == 0) { rl[wave][0] = l0; rl[wave][1] = l1; }
    __syncthreads();
    float L0 = rl[0][0] + rl[1][0] + rl[2][0] + rl[3][0] + gate_b[0];
    float L1 = rl[0][1] + rl[1][1] + rl[2][1] + rl[3][1] + gate_b[1];
    float mxl = fmaxf(L0, L1);
    float e0 = expf(L0 - mxl), e1 = expf(L1 - mxl);
    float g0 = e0 / (e0 + e1), g1 = e1 / (e0 + e1);
    float cw0 = ca_w[0], cw1 = ca_w[1], cw2 = ca_w[2];
    float rw0 = ra_w[0], rw1 = ra_w[1], rw2 = ra_w[2];
#pragma unroll
    for (int j = 0; j < 3; j++) {
        int c = j * 256 + tid;
        float pm = (c > 0)      ? pooled[c - 1] : 0.f;
        float pc = pooled[c];
        float pp = (c < CH - 1) ? pooled[c + 1] : 0.f;
        float cas = 1.f / (1.f + expf(-(cw0 * pm + cw1 * pc + cw2 * pp)));
        float ras = 1.f - 1.f / (1.f + expf(-(rw0 * pm + rw1 * pc + rw2 * pp)));
        scale[((size_t)s * 8 + b) * CH + c] = g0 * cas + g1 * ras;
    }
}

// recompute conv, apply scale + exact GELU, emit bf16 A-matrix for fc2. grid (21, 3, 8)
__global__ void k_apply(const u16* __restrict__ h, const float* __restrict__ dw_w,
                        const float* __restrict__ dw_b, const float* __restrict__ scale,
                        u16* __restrict__ g) {
    int slot = blockIdx.x, cchunk = blockIdx.y, b = blockIdx.z;
    int s, chunk, tokbase, lw;
    decode_slot(slot, s, chunk, tokbase, lw);
    int hw = 1 << lw;
    int c = cchunk * 256 + threadIdx.x;
    float sc = scale[((size_t)s * 8 + b) * CH + c];
    float wreg[9];
#pragma unroll
    for (int i = 0; i < 9; i++) wreg[i] = dw_w[c * 9 + i];
    float dwb = dw_b[c];
    int p0 = chunk * 256;
    for (int p = p0; p < p0 + 256; ++p) {
        float v = conv_at(h, wreg, dwb, b, tokbase, hw, lw, p, c) * sc;
        float gl = 0.5f * v * (1.f + erff(v * 0.70710678118654752f));
        g[((size_t)(b * NTOK + tokbase + p)) * CH + c] = f2bf(gl);
    }
}

// ---------------------------------------------------------------- launch
extern "C" void kernel_launch(void* const* d_in, const int* in_sizes, int n_in,
                              void* d_out, int out_size, void* d_ws, size_t ws_size,
                              hipStream_t stream) {
    const float* x      = (const float*)d_in[0];
    const float* fc1_w  = (const float*)d_in[1];
    const float* fc1_b  = (const float*)d_in[2];
    const float* dw_w   = (const float*)d_in[3];
    const float* dw_b   = (const float*)d_in[4];
    const float* ca_w   = (const float*)d_in[5];
    const float* ra_w   = (const float*)d_in[6];
    const float* gate_w = (const float*)d_in[7];
    const float* gate_b = (const float*)d_in[8];
    const float* fc2_w  = (const float*)d_in[9];
    const float* fc2_b  = (const float*)d_in[10];

    char* ws = (char*)d_ws;
    u16*  xb    = (u16*)(ws);                    // 43008*384*2  = 33,030,144
    u16*  hb    = (u16*)(ws + 33030144);         // 43008*768*2  = 66,060,288
    u16*  gbuf  = (u16*)(ws + 99090432);         // 43008*768*2  = 66,060,288
    u16*  w1T   = (u16*)(ws + 165150720);        // 768*384*2    =    589,824
    u16*  w2T   = (u16*)(ws + 165740544);        // 384*768*2    =    589,824
    float* psum = (float*)(ws + 166330368);      // 21*8*768*4   =    516,096
    float* pmax = (float*)(ws + 166846464);      // 21*8*768*4   =    516,096
    float* scale= (float*)(ws + 167362560);      // 3*8*768*4    =     73,728

    // 1) dtype conversions
    k_cvt_x<<<16128, 256, 0, stream>>>(x, xb, (M_ * CIN) / 4);
    k_cvt_wT<<<(CIN * CH + 255) / 256, 256, 0, stream>>>(fc1_w, w1T, CIN, CH);
    k_cvt_wT<<<(CIN * CH + 255) / 256, 256, 0, stream>>>(fc2_w, w2T, CH, CIN);

    // 2) fc1: (43008 x 384) @ (384 x 768) -> h bf16
    gemm_bf16_kernel<true><<<dim3(M_ / BM, CH / BN), 256, 0, stream>>>(
        xb, w1T, fc1_b, (void*)hb, M_, CH, CIN);

    // 3) depthwise conv + pooled stats (partials, no atomics)
    k_conv_stats<<<dim3(21, 3, 8), 256, 0, stream>>>(hb, dw_w, dw_b, psum, pmax);

    // 4) per-(scale,b) gate/scale computation
    k_scale<<<dim3(3, 8), 256, 0, stream>>>(psum, pmax, gate_w, gate_b, ca_w, ra_w, scale);

    // 5) conv recompute + scale + GELU -> g bf16
    k_apply<<<dim3(21, 3, 8), 256, 0, stream>>>(hb, dw_w, dw_b, scale, gbuf);

    // 6) fc2: (43008 x 768) @ (768 x 384) + bias -> out f32
    gemm_bf16_kernel<false><<<dim3(M_ / BM, CIN / BN), 256, 0, stream>>>(
        gbuf, w2T, fc2_b, d_out, M_, CIN, CH);
}

// Round 3
// 373.396 us; speedup vs baseline: 3.6045x; 3.6045x over previous
//
#include <hip/hip_runtime.h>
#include <math.h>

#define B_   8
#define NTOK 5376
#define CIN  384
#define CH   768
#define M_   (B_*NTOK)   // 43008

typedef unsigned short u16;
typedef unsigned int   u32;

using bf16x8 = __attribute__((ext_vector_type(8))) short;
using bf16x4 = __attribute__((ext_vector_type(4))) short;
using f32x4  = __attribute__((ext_vector_type(4))) float;

__device__ __forceinline__ u16 f2bf(float f) {
    union { float f; u32 u; } v; v.f = f;
    u32 r = v.u + 0x7fffu + ((v.u >> 16) & 1u);   // RNE (finite inputs)
    return (u16)(r >> 16);
}
__device__ __forceinline__ float bf2f(u16 u) {
    union { u32 u; float f; } v; v.u = ((u32)u) << 16;
    return v.f;
}

// ---------------------------------------------------------------- converts
__global__ void k_cvt_x(const float* __restrict__ x, u16* __restrict__ xb, int n4) {
    int i = blockIdx.x * blockDim.x + threadIdx.x;
    if (i >= n4) return;
    float4 v = ((const float4*)x)[i];
    ushort4 o;
    o.x = f2bf(v.x); o.y = f2bf(v.y); o.z = f2bf(v.z); o.w = f2bf(v.w);
    ((ushort4*)xb)[i] = o;
}

// src: (K, N) f32 row-major  ->  dst: (N, K) bf16 row-major
__global__ void k_cvt_wT(const float* __restrict__ w, u16* __restrict__ wT, int K, int N) {
    int i = blockIdx.x * blockDim.x + threadIdx.x;
    if (i >= N * K) return;
    int n = i / K, k = i % K;
    wT[i] = f2bf(w[k * N + n]);
}

// ---------------------------------------------------------------- GEMM
// C[M,N] = A[M,K] @ Bt[N,K]^T + bias, A/Bt bf16, acc f32.
// 128x128 tile, BK=64, 4 waves (2x2), 16x16x32 MFMA, global_load_lds staging.
#define BM 128
#define BN 128
#define BK 64

template<bool OUT_BF16>
__launch_bounds__(256)
__global__ void gemm_bf16_kernel(const u16* __restrict__ A, const u16* __restrict__ Bt,
                                 const float* __restrict__ bias, void* __restrict__ Cout,
                                 int M, int N, int K) {
    __shared__ __align__(16) u16 sA[BM * BK];
    __shared__ __align__(16) u16 sB[BN * BK];
    const int mt = blockIdx.x, nt = blockIdx.y;
    const int tid = threadIdx.x;
    const int wave = tid >> 6, lane = tid & 63;
    const int wm = wave >> 1, wn = wave & 1;
    const int row0 = mt * BM, col0 = nt * BN;
    const int lr = lane & 15, lk = lane >> 4;

    f32x4 acc[4][4];
#pragma unroll
    for (int m = 0; m < 4; m++)
#pragma unroll
        for (int n = 0; n < 4; n++) acc[m][n] = (f32x4){0.f, 0.f, 0.f, 0.f};

    const int KT = K / BK;
    for (int kt = 0; kt < KT; ++kt) {
        const int k0 = kt * BK;
#pragma unroll
        for (int it = 0; it < 4; ++it) {
            int g  = it * 256 + tid;
            int r  = g >> 3;
            int ks = g & 7;
            const u16* gA = A + (size_t)(row0 + r) * K + k0 + ks * 8;
            const u16* gB = Bt + (size_t)(col0 + r) * K + k0 + ks * 8;
            u16* lA = sA + (size_t)(it * 256 + wave * 64) * 8;   // wave-uniform base
            u16* lB = sB + (size_t)(it * 256 + wave * 64) * 8;
            __builtin_amdgcn_global_load_lds(
                (const __attribute__((address_space(1))) u32*)(const void*)gA,
                (__attribute__((address_space(3))) u32*)(void*)lA, 16, 0, 0);
            __builtin_amdgcn_global_load_lds(
                (const __attribute__((address_space(1))) u32*)(const void*)gB,
                (__attribute__((address_space(3))) u32*)(void*)lB, 16, 0, 0);
        }
        __syncthreads();
#pragma unroll
        for (int kk = 0; kk < 2; ++kk) {
            bf16x8 af[4], bfr[4];
#pragma unroll
            for (int m = 0; m < 4; m++)
                af[m] = *(const bf16x8*)&sA[(wm * 64 + m * 16 + lr) * BK + kk * 32 + lk * 8];
#pragma unroll
            for (int n = 0; n < 4; n++)
                bfr[n] = *(const bf16x8*)&sB[(wn * 64 + n * 16 + lr) * BK + kk * 32 + lk * 8];
#pragma unroll
            for (int m = 0; m < 4; m++)
#pragma unroll
                for (int n = 0; n < 4; n++)
                    acc[m][n] = __builtin_amdgcn_mfma_f32_16x16x32_bf16(af[m], bfr[n], acc[m][n], 0, 0, 0);
        }
        __syncthreads();
    }

#pragma unroll
    for (int m = 0; m < 4; m++) {
#pragma unroll
        for (int n = 0; n < 4; n++) {
            int col = col0 + wn * 64 + n * 16 + lr;
            float bv = bias[col];
#pragma unroll
            for (int r = 0; r < 4; r++) {
                int row = row0 + wm * 64 + m * 16 + lk * 4 + r;
                float v = acc[m][n][r] + bv;
                if (OUT_BF16)
                    ((u16*)Cout)[(size_t)row * N + col] = f2bf(v);
                else
                    ((float*)Cout)[(size_t)row * N + col] = v;
            }
        }
    }
}

// ---------------------------------------------------------------- conv pass
// One block per (xflat, b): walks y with a 3x3 register window, 192 threads =
// 192 channel-quads. Emits xs (bf16) + per-column partial sum/max.
// xflat: 0..63 -> s0 (64x64), 64..95 -> s1 (32x32), 96..111 -> s2 (16x16)
__launch_bounds__(192)
__global__ void k_conv(const u16* __restrict__ h, const float* __restrict__ dw_w,
                       const float* __restrict__ dw_b, u16* __restrict__ xs,
                       float* __restrict__ psum, float* __restrict__ pmax) {
    const int xflat = blockIdx.x, b = blockIdx.y;
    int x, tokbase, LW;
    if (xflat < 64)      { x = xflat;      tokbase = 0;    LW = 6; }
    else if (xflat < 96) { x = xflat - 64; tokbase = 4096; LW = 5; }
    else                 { x = xflat - 96; tokbase = 5120; LW = 4; }
    const int W = 1 << LW, H = W;
    const int c4 = threadIdx.x, c0 = c4 * 4;

    float wv[3][3][4], dwb[4];
#pragma unroll
    for (int j = 0; j < 4; j++) {
        dwb[j] = dw_b[c0 + j];
#pragma unroll
        for (int t = 0; t < 9; t++) wv[t / 3][t % 3][j] = dw_w[(c0 + j) * 9 + t];
    }

    const size_t colbase = ((size_t)(b * NTOK + tokbase + x)) * CH + c0;
    const int RS = W * CH;
    const bool xm = (x > 0), xp = (x < W - 1);
    const bf16x4 z4 = (bf16x4){0, 0, 0, 0};

    bf16x4 r0[3], r1[3], r2[3];
#pragma unroll
    for (int cidx = 0; cidx < 3; cidx++) r0[cidx] = z4;
    r1[0] = xm ? *(const bf16x4*)&h[colbase - CH] : z4;
    r1[1] = *(const bf16x4*)&h[colbase];
    r1[2] = xp ? *(const bf16x4*)&h[colbase + CH] : z4;

    float as[4] = {0.f, 0.f, 0.f, 0.f};
    float am[4] = {-3.4e38f, -3.4e38f, -3.4e38f, -3.4e38f};

#pragma unroll 2
    for (int y = 0; y < H; ++y) {
        if (y + 1 < H) {
            size_t rb = colbase + (size_t)(y + 1) * RS;
            r2[0] = xm ? *(const bf16x4*)&h[rb - CH] : z4;
            r2[1] = *(const bf16x4*)&h[rb];
            r2[2] = xp ? *(const bf16x4*)&h[rb + CH] : z4;
        } else {
            r2[0] = z4; r2[1] = z4; r2[2] = z4;
        }
        float o[4];
#pragma unroll
        for (int j = 0; j < 4; j++) o[j] = dwb[j];
#pragma unroll
        for (int cidx = 0; cidx < 3; cidx++) {
#pragma unroll
            for (int j = 0; j < 4; j++) {
                o[j] += wv[0][cidx][j] * bf2f((u16)r0[cidx][j]);
                o[j] += wv[1][cidx][j] * bf2f((u16)r1[cidx][j]);
                o[j] += wv[2][cidx][j] * bf2f((u16)r2[cidx][j]);
            }
        }
        bf16x4 ov;
#pragma unroll
        for (int j = 0; j < 4; j++) {
            ov[j] = (short)f2bf(o[j]);
            as[j] += o[j];
            am[j] = fmaxf(am[j], o[j]);
        }
        *(bf16x4*)&xs[colbase + (size_t)y * RS] = ov;
#pragma unroll
        for (int cidx = 0; cidx < 3; cidx++) { r0[cidx] = r1[cidx]; r1[cidx] = r2[cidx]; }
    }

    float4 s4 = make_float4(as[0], as[1], as[2], as[3]);
    float4 m4 = make_float4(am[0], am[1], am[2], am[3]);
    size_t pidx = ((size_t)xflat * 8 + b) * CH + c0;
    *(float4*)&psum[pidx] = s4;
    *(float4*)&pmax[pidx] = m4;
}

// reduce partials -> gate softmax, channel conv1 gates, blended scale. grid (3, 8)
__global__ void k_scale(const float* __restrict__ psum, const float* __restrict__ pmax,
                        const float* __restrict__ gate_w, const float* __restrict__ gate_b,
                        const float* __restrict__ ca_w, const float* __restrict__ ra_w,
                        float* __restrict__ scale) {
    int s = blockIdx.x, b = blockIdx.y;
    int tid = threadIdx.x;
    int slot0  = (s == 0) ? 0 : (s == 1) ? 64 : 96;
    int nslots = (s == 0) ? 64 : (s == 1) ? 32 : 16;
    float npos = (s == 0) ? 4096.f : (s == 1) ? 1024.f : 256.f;
    __shared__ float pooled[CH];
    __shared__ float rl[4][2];
    float l0 = 0.f, l1 = 0.f;
#pragma unroll
    for (int j = 0; j < 3; j++) {
        int c = j * 256 + tid;
        float smv = 0.f, mxv = -3.4e38f;
        for (int t = 0; t < nslots; t++) {
            size_t idx = ((size_t)(slot0 + t) * 8 + b) * CH + c;
            smv += psum[idx];
            mxv = fmaxf(mxv, pmax[idx]);
        }
        float avg = smv / npos;
        pooled[c] = avg + mxv;
        l0 += avg * gate_w[c * 2 + 0];
        l1 += avg * gate_w[c * 2 + 1];
    }
    for (int off = 32; off; off >>= 1) {
        l0 += __shfl_down(l0, off);
        l1 += __shfl_down(l1, off);
    }
    int wave = tid >> 6, lane = tid & 63;
    if (lane == 0) { rl[wave][0] = l0; rl[wave][1] = l1; }
    __syncthreads();
    float L0 = rl[0][0] + rl[1][0] + rl[2][0] + rl[3][0] + gate_b[0];
    float L1 = rl[0][1] + rl[1][1] + rl[2][1] + rl[3][1] + gate_b[1];
    float mxl = fmaxf(L0, L1);
    float e0 = expf(L0 - mxl), e1 = expf(L1 - mxl);
    float g0 = e0 / (e0 + e1), g1 = e1 / (e0 + e1);
    float cw0 = ca_w[0], cw1 = ca_w[1], cw2 = ca_w[2];
    float rw0 = ra_w[0], rw1 = ra_w[1], rw2 = ra_w[2];
#pragma unroll
    for (int j = 0; j < 3; j++) {
        int c = j * 256 + tid;
        float pm = (c > 0)      ? pooled[c - 1] : 0.f;
        float pc = pooled[c];
        float pp = (c < CH - 1) ? pooled[c + 1] : 0.f;
        float cas = 1.f / (1.f + expf(-(cw0 * pm + cw1 * pc + cw2 * pp)));
        float ras = 1.f - 1.f / (1.f + expf(-(rw0 * pm + rw1 * pc + rw2 * pp)));
        scale[((size_t)s * 8 + b) * CH + c] = g0 * cas + g1 * ras;
    }
}

// streaming: xs <- bf16(GELU(xs * scale)) in place. grid-stride over c8-groups.
#define NG (M_ * (CH / 8))
__global__ void k_apply(u16* __restrict__ xs, const float* __restrict__ scale) {
    for (int gi = blockIdx.x * blockDim.x + threadIdx.x; gi < NG;
         gi += gridDim.x * blockDim.x) {
        int c8 = gi % 96;
        int tl = gi / 96;            // b*5376 + t
        int t = tl % NTOK, b = tl / NTOK;
        int s = (t < 4096) ? 0 : (t < 5120 ? 1 : 2);
        const float4* sp = (const float4*)&scale[((size_t)(s * 8 + b)) * CH + c8 * 8];
        float4 sc0 = sp[0], sc1 = sp[1];
        float scv[8] = {sc0.x, sc0.y, sc0.z, sc0.w, sc1.x, sc1.y, sc1.z, sc1.w};
        bf16x8 v = *(const bf16x8*)&xs[(size_t)gi * 8];
        bf16x8 o;
#pragma unroll
        for (int j = 0; j < 8; j++) {
            float f = bf2f((u16)v[j]) * scv[j];
            float gl = 0.5f * f * (1.f + erff(f * 0.70710678118654752f));
            o[j] = (short)f2bf(gl);
        }
        *(bf16x8*)&xs[(size_t)gi * 8] = o;
    }
}

// ---------------------------------------------------------------- launch
extern "C" void kernel_launch(void* const* d_in, const int* in_sizes, int n_in,
                              void* d_out, int out_size, void* d_ws, size_t ws_size,
                              hipStream_t stream) {
    const float* x      = (const float*)d_in[0];
    const float* fc1_w  = (const float*)d_in[1];
    const float* fc1_b  = (const float*)d_in[2];
    const float* dw_w   = (const float*)d_in[3];
    const float* dw_b   = (const float*)d_in[4];
    const float* ca_w   = (const float*)d_in[5];
    const float* ra_w   = (const float*)d_in[6];
    const float* gate_w = (const float*)d_in[7];
    const float* gate_b = (const float*)d_in[8];
    const float* fc2_w  = (const float*)d_in[9];
    const float* fc2_b  = (const float*)d_in[10];

    char* ws = (char*)d_ws;
    u16*  xb    = (u16*)(ws);                    // 43008*384*2  = 33,030,144 (dead after fc1)
    u16*  hb    = (u16*)(ws + 33030144);         // 43008*768*2  = 66,060,288
    u16*  xs    = (u16*)(ws + 99090432);         // 43008*768*2  = 66,060,288 (conv out; GELU in place)
    u16*  w1T   = (u16*)(ws + 165150720);        // 768*384*2    =    589,824
    u16*  w2T   = (u16*)(ws + 165740544);        // 384*768*2    =    589,824
    // stats overlay the xb region (only used after fc1 has consumed xb)
    float* psum = (float*)(ws);                  // 112*8*768*4  =  2,752,512
    float* pmax = (float*)(ws + 2752512);        // 112*8*768*4  =  2,752,512
    float* scale= (float*)(ws + 5505024);        // 3*8*768*4    =     73,728

    // 1) dtype conversions
    k_cvt_x<<<16128, 256, 0, stream>>>(x, xb, (M_ * CIN) / 4);
    k_cvt_wT<<<(CIN * CH + 255) / 256, 256, 0, stream>>>(fc1_w, w1T, CIN, CH);
    k_cvt_wT<<<(CIN * CH + 255) / 256, 256, 0, stream>>>(fc2_w, w2T, CH, CIN);

    // 2) fc1: (43008 x 384) @ (384 x 768) -> h bf16
    gemm_bf16_kernel<true><<<dim3(M_ / BM, CH / BN), 256, 0, stream>>>(
        xb, w1T, fc1_b, (void*)hb, M_, CH, CIN);

    // 3) depthwise conv (register sliding window) -> xs + partial stats
    k_conv<<<dim3(112, 8), 192, 0, stream>>>(hb, dw_w, dw_b, xs, psum, pmax);

    // 4) per-(scale,b) gate/scale computation
    k_scale<<<dim3(3, 8), 256, 0, stream>>>(psum, pmax, gate_w, gate_b, ca_w, ra_w, scale);

    // 5) streaming scale + exact GELU, in place on xs
    k_apply<<<4096, 256, 0, stream>>>(xs, scale);

    // 6) fc2: (43008 x 768) @ (768 x 384) + bias -> out f32
    gemm_bf16_kernel<false><<<dim3(M_ / BM, CIN / BN), 256, 0, stream>>>(
        xs, w2T, fc2_b, d_out, M_, CIN, CH);
}

// Round 4
// 336.680 us; speedup vs baseline: 3.9976x; 1.1091x over previous
//
#include <hip/hip_runtime.h>
#include <math.h>

#define B_   8
#define NTOK 5376
#define CIN  384
#define CH   768
#define M_   (B_*NTOK)   // 43008

typedef unsigned short u16;
typedef unsigned int   u32;

using bf16x8 = __attribute__((ext_vector_type(8))) short;
using bf16x4 = __attribute__((ext_vector_type(4))) short;
using f32x4  = __attribute__((ext_vector_type(4))) float;

__device__ __forceinline__ u16 f2bf(float f) {
    union { float f; u32 u; } v; v.f = f;
    u32 r = v.u + 0x7fffu + ((v.u >> 16) & 1u);   // RNE (finite inputs)
    return (u16)(r >> 16);
}
__device__ __forceinline__ float bf2f(u16 u) {
    union { u32 u; float f; } v; v.u = ((u32)u) << 16;
    return v.f;
}
// monotonic order-preserving f32 <-> u32 key (for atomicMax); key(any real) > 0
__device__ __forceinline__ u32 fkey(float f) {
    union { float f; u32 u; } v; v.f = f;
    return (v.u & 0x80000000u) ? ~v.u : (v.u | 0x80000000u);
}
__device__ __forceinline__ float fkeyinv(u32 k) {
    union { u32 u; float f; } v;
    v.u = (k & 0x80000000u) ? (k ^ 0x80000000u) : ~k;
    return v.f;
}

// ---------------------------------------------------------------- converts
__global__ void k_cvt_x(const float* __restrict__ x, u16* __restrict__ xb, int n8) {
    int i = blockIdx.x * blockDim.x + threadIdx.x;
    if (i >= n8) return;
    float4 a = ((const float4*)x)[2 * i];
    float4 b = ((const float4*)x)[2 * i + 1];
    bf16x8 o;
    o[0] = (short)f2bf(a.x); o[1] = (short)f2bf(a.y);
    o[2] = (short)f2bf(a.z); o[3] = (short)f2bf(a.w);
    o[4] = (short)f2bf(b.x); o[5] = (short)f2bf(b.y);
    o[6] = (short)f2bf(b.z); o[7] = (short)f2bf(b.w);
    ((bf16x8*)xb)[i] = o;
}

// src: (K, N) f32 row-major  ->  dst: (N, K) bf16 row-major
__global__ void k_cvt_wT(const float* __restrict__ w, u16* __restrict__ wT, int K, int N) {
    int i = blockIdx.x * blockDim.x + threadIdx.x;
    if (i >= N * K) return;
    int n = i / K, k = i % K;
    wT[i] = f2bf(w[k * N + n]);
}

// ---------------------------------------------------------------- GEMM
#define BM 128
#define BN 128
#define BK 64

template<bool OUT_BF16>
__launch_bounds__(256)
__global__ void gemm_bf16_kernel(const u16* __restrict__ A, const u16* __restrict__ Bt,
                                 const float* __restrict__ bias, void* __restrict__ Cout,
                                 int M, int N, int K) {
    __shared__ __align__(16) u16 sA[BM * BK];
    __shared__ __align__(16) u16 sB[BN * BK];
    const int mt = blockIdx.x, nt = blockIdx.y;
    const int tid = threadIdx.x;
    const int wave = tid >> 6, lane = tid & 63;
    const int wm = wave >> 1, wn = wave & 1;
    const int row0 = mt * BM, col0 = nt * BN;
    const int lr = lane & 15, lk = lane >> 4;

    f32x4 acc[4][4];
#pragma unroll
    for (int m = 0; m < 4; m++)
#pragma unroll
        for (int n = 0; n < 4; n++) acc[m][n] = (f32x4){0.f, 0.f, 0.f, 0.f};

    const int KT = K / BK;
    for (int kt = 0; kt < KT; ++kt) {
        const int k0 = kt * BK;
#pragma unroll
        for (int it = 0; it < 4; ++it) {
            int g  = it * 256 + tid;
            int r  = g >> 3;
            int ks = g & 7;
            const u16* gA = A + (size_t)(row0 + r) * K + k0 + ks * 8;
            const u16* gB = Bt + (size_t)(col0 + r) * K + k0 + ks * 8;
            u16* lA = sA + (size_t)(it * 256 + wave * 64) * 8;   // wave-uniform base
            u16* lB = sB + (size_t)(it * 256 + wave * 64) * 8;
            __builtin_amdgcn_global_load_lds(
                (const __attribute__((address_space(1))) u32*)(const void*)gA,
                (__attribute__((address_space(3))) u32*)(void*)lA, 16, 0, 0);
            __builtin_amdgcn_global_load_lds(
                (const __attribute__((address_space(1))) u32*)(const void*)gB,
                (__attribute__((address_space(3))) u32*)(void*)lB, 16, 0, 0);
        }
        __syncthreads();
#pragma unroll
        for (int kk = 0; kk < 2; ++kk) {
            bf16x8 af[4], bfr[4];
#pragma unroll
            for (int m = 0; m < 4; m++)
                af[m] = *(const bf16x8*)&sA[(wm * 64 + m * 16 + lr) * BK + kk * 32 + lk * 8];
#pragma unroll
            for (int n = 0; n < 4; n++)
                bfr[n] = *(const bf16x8*)&sB[(wn * 64 + n * 16 + lr) * BK + kk * 32 + lk * 8];
#pragma unroll
            for (int m = 0; m < 4; m++)
#pragma unroll
                for (int n = 0; n < 4; n++)
                    acc[m][n] = __builtin_amdgcn_mfma_f32_16x16x32_bf16(af[m], bfr[n], acc[m][n], 0, 0, 0);
        }
        __syncthreads();
    }

#pragma unroll
    for (int m = 0; m < 4; m++) {
#pragma unroll
        for (int n = 0; n < 4; n++) {
            int col = col0 + wn * 64 + n * 16 + lr;
            float bv = bias[col];
#pragma unroll
            for (int r = 0; r < 4; r++) {
                int row = row0 + wm * 64 + m * 16 + lk * 4 + r;
                float v = acc[m][n][r] + bv;
                if (OUT_BF16)
                    ((u16*)Cout)[(size_t)row * N + col] = f2bf(v);
                else
                    ((float*)Cout)[(size_t)row * N + col] = v;
            }
        }
    }
}

// ---------------------------------------------------------------- conv pass
// 2-D tiled: one block per (tile, b); tile = 8x8 positions, 192 threads = 192
// channel-quads. 3-row circular register window (compile-time slots), fully
// unrolled. Stats accumulated straight into [3][8][768] via atomics.
// tiles: 0..63 -> s0 (8x8 grid), 64..79 -> s1 (4x4), 80..83 -> s2 (2x2)
__launch_bounds__(192)
__global__ void k_conv(const u16* __restrict__ h, const float* __restrict__ dw_w,
                       const float* __restrict__ dw_b, u16* __restrict__ xs,
                       float* __restrict__ psum, u32* __restrict__ pmaxk) {
    const int tile = blockIdx.x, b = blockIdx.y;
    int s, xt, yt, tokbase, LW;
    if (tile < 64)      { s = 0; xt = tile & 7;  yt = tile >> 3; tokbase = 0;    LW = 6; }
    else if (tile < 80) { int u = tile - 64; s = 1; xt = u & 3; yt = u >> 2; tokbase = 4096; LW = 5; }
    else                { int u = tile - 80; s = 2; xt = u & 1; yt = u >> 1; tokbase = 5120; LW = 4; }
    const int W = 1 << LW, H = W;
    const int x0 = xt * 8, y0 = yt * 8;
    const int c0 = threadIdx.x * 4;

    float wv[9][4], dwb[4];
#pragma unroll
    for (int j = 0; j < 4; j++) {
        dwb[j] = dw_b[c0 + j];
#pragma unroll
        for (int t = 0; t < 9; t++) wv[t][j] = dw_w[(c0 + j) * 9 + t];
    }

    const size_t base = ((size_t)(b * NTOK + tokbase)) * CH + c0;
    const bf16x4 z4 = (bf16x4){0, 0, 0, 0};
    bool colv[10];
    int coloff[10];
#pragma unroll
    for (int j = 0; j < 10; j++) {
        int xx = x0 - 1 + j;
        colv[j] = (xx >= 0) && (xx < W);
        coloff[j] = xx * CH;
    }

    bf16x4 r[3][10];

#define LOADROW(slot, yrow) {                                                   \
        int yr_ = (yrow);                                                       \
        bool rv_ = ((unsigned)yr_ < (unsigned)H);                               \
        int rb_ = yr_ * W * CH;                                                 \
        _Pragma("unroll")                                                       \
        for (int j = 0; j < 10; j++)                                            \
            r[slot][j] = (rv_ && colv[j]) ? *(const bf16x4*)&h[base + rb_ + coloff[j]] : z4; \
    }

    LOADROW(0, y0 - 1);
    LOADROW(1, y0);

    float as[4] = {0.f, 0.f, 0.f, 0.f};
    float am[4] = {-3.4e38f, -3.4e38f, -3.4e38f, -3.4e38f};

#pragma unroll
    for (int yy = 0; yy < 8; ++yy) {
        const int sm1 = yy % 3, sc = (yy + 1) % 3, sp1 = (yy + 2) % 3;
        LOADROW(sp1, y0 + yy + 1);
        const int orow = (y0 + yy) * W * CH;
#pragma unroll
        for (int p = 0; p < 8; ++p) {
            float o[4];
#pragma unroll
            for (int j = 0; j < 4; j++) o[j] = dwb[j];
#pragma unroll
            for (int kx = 0; kx < 3; ++kx) {
                const int ci = p + kx;
#pragma unroll
                for (int j = 0; j < 4; j++) {
                    o[j] += wv[0 + kx][j] * bf2f((u16)r[sm1][ci][j]);
                    o[j] += wv[3 + kx][j] * bf2f((u16)r[sc ][ci][j]);
                    o[j] += wv[6 + kx][j] * bf2f((u16)r[sp1][ci][j]);
                }
            }
            bf16x4 ov;
#pragma unroll
            for (int j = 0; j < 4; j++) {
                ov[j] = (short)f2bf(o[j]);
                as[j] += o[j];
                am[j] = fmaxf(am[j], o[j]);
            }
            *(bf16x4*)&xs[base + orow + (x0 + p) * CH] = ov;
        }
    }
#undef LOADROW

#pragma unroll
    for (int j = 0; j < 4; j++) {
        atomicAdd(&psum[(s * 8 + b) * CH + c0 + j], as[j]);
        atomicMax(&pmaxk[(s * 8 + b) * CH + c0 + j], fkey(am[j]));
    }
}

// gate softmax + channel conv1 gates + blended scale. grid (3, 8)
__global__ void k_scale(const float* __restrict__ psum, const u32* __restrict__ pmaxk,
                        const float* __restrict__ gate_w, const float* __restrict__ gate_b,
                        const float* __restrict__ ca_w, const float* __restrict__ ra_w,
                        float* __restrict__ scale) {
    int s = blockIdx.x, b = blockIdx.y;
    int tid = threadIdx.x;
    float npos = (s == 0) ? 4096.f : (s == 1) ? 1024.f : 256.f;
    __shared__ float pooled[CH];
    __shared__ float rl[4][2];
    float l0 = 0.f, l1 = 0.f;
#pragma unroll
    for (int j = 0; j < 3; j++) {
        int c = j * 256 + tid;
        size_t idx = ((size_t)s * 8 + b) * CH + c;
        float avg = psum[idx] / npos;
        float mxv = fkeyinv(pmaxk[idx]);
        pooled[c] = avg + mxv;
        l0 += avg * gate_w[c * 2 + 0];
        l1 += avg * gate_w[c * 2 + 1];
    }
    for (int off = 32; off; off >>= 1) {
        l0 += __shfl_down(l0, off);
        l1 += __shfl_down(l1, off);
    }
    int wave = tid >> 6, lane = tid & 63;
    if (lane == 0) { rl[wave][0] = l0; rl[wave][1] = l1; }
    __syncthreads();
    float L0 = rl[0][0] + rl[1][0] + rl[2][0] + rl[3][0] + gate_b[0];
    float L1 = rl[0][1] + rl[1][1] + rl[2][1] + rl[3][1] + gate_b[1];
    float mxl = fmaxf(L0, L1);
    float e0 = expf(L0 - mxl), e1 = expf(L1 - mxl);
    float g0 = e0 / (e0 + e1), g1 = e1 / (e0 + e1);
    float cw0 = ca_w[0], cw1 = ca_w[1], cw2 = ca_w[2];
    float rw0 = ra_w[0], rw1 = ra_w[1], rw2 = ra_w[2];
#pragma unroll
    for (int j = 0; j < 3; j++) {
        int c = j * 256 + tid;
        float pm = (c > 0)      ? pooled[c - 1] : 0.f;
        float pc = pooled[c];
        float pp = (c < CH - 1) ? pooled[c + 1] : 0.f;
        float cas = 1.f / (1.f + expf(-(cw0 * pm + cw1 * pc + cw2 * pp)));
        float ras = 1.f - 1.f / (1.f + expf(-(rw0 * pm + rw1 * pc + rw2 * pp)));
        scale[((size_t)s * 8 + b) * CH + c] = g0 * cas + g1 * ras;
    }
}

// streaming: xs <- bf16(GELU(xs * scale)) in place. grid-stride over c8-groups.
#define NG (M_ * (CH / 8))
__global__ void k_apply(u16* __restrict__ xs, const float* __restrict__ scale) {
    for (int gi = blockIdx.x * blockDim.x + threadIdx.x; gi < NG;
         gi += gridDim.x * blockDim.x) {
        int c8 = gi % 96;
        int tl = gi / 96;            // b*5376 + t
        int t = tl % NTOK, b = tl / NTOK;
        int s = (t < 4096) ? 0 : (t < 5120 ? 1 : 2);
        const float4* sp = (const float4*)&scale[((size_t)(s * 8 + b)) * CH + c8 * 8];
        float4 sc0 = sp[0], sc1 = sp[1];
        float scv[8] = {sc0.x, sc0.y, sc0.z, sc0.w, sc1.x, sc1.y, sc1.z, sc1.w};
        bf16x8 v = *(const bf16x8*)&xs[(size_t)gi * 8];
        bf16x8 o;
#pragma unroll
        for (int j = 0; j < 8; j++) {
            float f = bf2f((u16)v[j]) * scv[j];
            float gl = 0.5f * f * (1.f + erff(f * 0.70710678118654752f));
            o[j] = (short)f2bf(gl);
        }
        *(bf16x8*)&xs[(size_t)gi * 8] = o;
    }
}

// ---------------------------------------------------------------- launch
extern "C" void kernel_launch(void* const* d_in, const int* in_sizes, int n_in,
                              void* d_out, int out_size, void* d_ws, size_t ws_size,
                              hipStream_t stream) {
    const float* x      = (const float*)d_in[0];
    const float* fc1_w  = (const float*)d_in[1];
    const float* fc1_b  = (const float*)d_in[2];
    const float* dw_w   = (const float*)d_in[3];
    const float* dw_b   = (const float*)d_in[4];
    const float* ca_w   = (const float*)d_in[5];
    const float* ra_w   = (const float*)d_in[6];
    const float* gate_w = (const float*)d_in[7];
    const float* gate_b = (const float*)d_in[8];
    const float* fc2_w  = (const float*)d_in[9];
    const float* fc2_b  = (const float*)d_in[10];

    char* ws = (char*)d_ws;
    u16*  xb    = (u16*)(ws);                    // 43008*384*2  = 33,030,144
    u16*  hb    = (u16*)(ws + 33030144);         // 43008*768*2  = 66,060,288
    u16*  xs    = (u16*)(ws + 99090432);         // 43008*768*2  = 66,060,288
    u16*  w1T   = (u16*)(ws + 165150720);        // 768*384*2    =    589,824
    u16*  w2T   = (u16*)(ws + 165740544);        // 384*768*2    =    589,824
    float* psum = (float*)(ws + 166330368);      // 3*8*768*4    =     73,728
    u32*  pmaxk = (u32*)(ws + 166404096);        // 3*8*768*4    =     73,728
    float* scale= (float*)(ws + 166477824);      // 3*8*768*4    =     73,728

    // 0) zero the atomic accumulators (psum=0; pmaxk key 0 < key(any real))
    hipMemsetAsync((void*)psum, 0, 147456, stream);

    // 1) dtype conversions
    k_cvt_x<<<(M_ * CIN / 8 + 255) / 256, 256, 0, stream>>>(x, xb, M_ * CIN / 8);
    k_cvt_wT<<<(CIN * CH + 255) / 256, 256, 0, stream>>>(fc1_w, w1T, CIN, CH);
    k_cvt_wT<<<(CIN * CH + 255) / 256, 256, 0, stream>>>(fc2_w, w2T, CH, CIN);

    // 2) fc1: (43008 x 384) @ (384 x 768) -> h bf16
    gemm_bf16_kernel<true><<<dim3(M_ / BM, CH / BN), 256, 0, stream>>>(
        xb, w1T, fc1_b, (void*)hb, M_, CH, CIN);

    // 3) depthwise conv (2-D tiled register window) -> xs + atomic stats
    k_conv<<<dim3(84, 8), 192, 0, stream>>>(hb, dw_w, dw_b, xs, psum, pmaxk);

    // 4) per-(scale,b) gate/scale computation
    k_scale<<<dim3(3, 8), 256, 0, stream>>>(psum, pmaxk, gate_w, gate_b, ca_w, ra_w, scale);

    // 5) streaming scale + exact GELU, in place on xs
    k_apply<<<4096, 256, 0, stream>>>(xs, scale);

    // 6) fc2: (43008 x 768) @ (768 x 384) + bias -> out f32
    gemm_bf16_kernel<false><<<dim3(M_ / BM, CIN / BN), 256, 0, stream>>>(
        xs, w2T, fc2_b, d_out, M_, CIN, CH);
}